// Round 4
// baseline (677.241 us; speedup 1.0000x reference)
//
#include <hip/hip_runtime.h>

// CrossAttentionPro on MI355X — Round 3:
//  + attnval: fused online-softmax + PV kernel (replaces softmax_rows +
//    cval GEMMs). Scores stream row-major == MFMA A-operand layout, so
//    exp is applied in-register; row stats in regs, alpha via shfl.
//  + LDS-coalesced epilogue for 128x128 F16STORE GEMMs (chained, catt).
// Structure: all matmuls NT, v stored transposed, catt_y2x computed
// transposed, CH chunked by 4 z to bound workspace (~203 MB).

typedef _Float16 half_t;
typedef _Float16 half8 __attribute__((ext_vector_type(8)));
typedef float floatx4 __attribute__((ext_vector_type(4)));

constexpr int Bc = 2, Tc = 2048, Mc = 1024, Cc = 512, Hc = 8, Dc = 64;
constexpr int CHUNK_Z = 4;

enum { EPI_F16STORE = 0, EPI_QKV = 1, EPI_PROJ = 2 };

struct EpiParams {
  half_t* h0;        // q / f16 out
  half_t* h1;        // k (QKV)
  half_t* h2;        // v^T (QKV)
  float* f0;         // final fp32 out (PROJ)
  const float* bias;
  float scale;
  int ldc;
  long bstride;
  int seq;
};

// async global->LDS, 16B per lane; dst must be wave-uniform base + lane*16.
__device__ __forceinline__ void gld_lds16(const half_t* g, half_t* l) {
  __builtin_amdgcn_global_load_lds(
      (const __attribute__((address_space(1))) void*)g,
      (__attribute__((address_space(3))) void*)l, 16, 0, 0);
}

// ---------------------------------------------------------------- GEMM (NT)
// C[r,c] = sum_k A[r,k] * Bt[c,k], f16 in, fp32 MFMA accum.
// Staging: unpadded [rows][32] LDS, lane fetches k-chunk (slot ^ ((row>>1)&3))
// so frag ds_read_b128s are 2-way max (free). F16STORE epilogue goes through
// a 32 KB LDS tile (slot-swizzled) for 16B-coalesced global stores.
template <int BM, int BN, int WMG, int WNG, int EPI>
__global__ __launch_bounds__(256) void gemm_nt(
    const half_t* __restrict__ A, const half_t* __restrict__ Bt,
    int K, int lda, int ldb, long bsA, long bsB, EpiParams ep)
{
  constexpr int BK = 32;
  constexpr int WTM = BM / WMG, WTN = BN / WNG;
  constexpr int MI = WTM / 16, NI = WTN / 16;
  constexpr int ACHUNKS = BM * 4;
  constexpr int BCHUNKS = BN * 4;
  constexpr int STAGE_HALFS = (BM + BN) * BK;
  constexpr int EPIL_HALFS = (EPI == EPI_F16STORE) ? BM * BN : 0;
  constexpr int SMEM_HALFS = STAGE_HALFS > EPIL_HALFS ? STAGE_HALFS : EPIL_HALFS;
  __shared__ __align__(16) half_t smem[SMEM_HALFS];
  half_t* As = smem;
  half_t* Bs = smem + BM * BK;

  const int tid = threadIdx.x;
  const int lane = tid & 63;
  const int wave = tid >> 6;
  const int wm = wave / WNG, wn = wave % WNG;
  const int r16 = lane & 15, g = lane >> 4;
  const int z = blockIdx.z;
  const long m0 = (long)blockIdx.y * BM;
  const long n0 = (long)blockIdx.x * BN;
  const half_t* Abase = A + (long)z * bsA + m0 * (long)lda;
  const half_t* Bbase = Bt + (long)z * bsB + n0 * (long)ldb;

  const int rA = wm * WTM + r16;
  const int rB = wn * WTN + r16;
  const int swA = (g ^ ((rA >> 1) & 3)) * 8;
  const int swB = (g ^ ((rB >> 1) & 3)) * 8;

  floatx4 acc[MI][NI];
#pragma unroll
  for (int mi = 0; mi < MI; ++mi)
#pragma unroll
    for (int ni = 0; ni < NI; ++ni)
      acc[mi][ni] = floatx4{0.f, 0.f, 0.f, 0.f};

  for (int kt = 0; kt < K; kt += BK) {
#pragma unroll
    for (int i = 0; i < (ACHUNKS + 255) / 256; ++i) {
      const int c = tid + i * 256;
      if (ACHUNKS % 256 == 0 || c < ACHUNKS) {
        const int row = c >> 2, js = c & 3;
        const int jg = js ^ ((row >> 1) & 3);
        gld_lds16(Abase + (long)row * lda + kt + jg * 8, As + c * 8);
      }
    }
#pragma unroll
    for (int i = 0; i < (BCHUNKS + 255) / 256; ++i) {
      const int c = tid + i * 256;
      if (BCHUNKS % 256 == 0 || c < BCHUNKS) {
        const int row = c >> 2, js = c & 3;
        const int jg = js ^ ((row >> 1) & 3);
        gld_lds16(Bbase + (long)row * ldb + kt + jg * 8, Bs + c * 8);
      }
    }
    __syncthreads();
    half8 aF[MI], bF[NI];
#pragma unroll
    for (int mi = 0; mi < MI; ++mi)
      aF[mi] = *reinterpret_cast<const half8*>(&As[(rA + mi * 16) * BK + swA]);
#pragma unroll
    for (int ni = 0; ni < NI; ++ni)
      bF[ni] = *reinterpret_cast<const half8*>(&Bs[(rB + ni * 16) * BK + swB]);
#pragma unroll
    for (int mi = 0; mi < MI; ++mi)
#pragma unroll
      for (int ni = 0; ni < NI; ++ni)
        acc[mi][ni] = __builtin_amdgcn_mfma_f32_16x16x32_f16(aF[mi], bF[ni], acc[mi][ni], 0, 0, 0);
    __syncthreads();
  }

  // epilogue: C/D layout col=lane&15, row=(lane>>4)*4+reg  [m89-verified]
  if constexpr (EPI == EPI_F16STORE) {
    // acc -> LDS (slot-swizzled) -> coalesced half8 stores
#pragma unroll
    for (int mi = 0; mi < MI; ++mi)
#pragma unroll
      for (int ni = 0; ni < NI; ++ni)
#pragma unroll
        for (int reg = 0; reg < 4; ++reg) {
          const int rl = wm * WTM + mi * 16 + g * 4 + reg;
          const int cl = wn * WTN + ni * 16 + r16;
          const int slot = (cl >> 3) ^ (rl & 15);
          smem[rl * BN + slot * 8 + (cl & 7)] = (half_t)(acc[mi][ni][reg] * ep.scale);
        }
    __syncthreads();
    half_t* dst = ep.h0 + (long)z * ep.bstride + m0 * (long)ep.ldc + n0;
    constexpr int CPT = (BM * BN) / (256 * 8);   // half8 chunks per thread
#pragma unroll
    for (int i = 0; i < CPT; ++i) {
      const int cc = tid * CPT + i;
      const int row = cc / (BN / 8), jc = cc % (BN / 8);
      const int slot = jc ^ (row & 15);
      const half8 hv = *reinterpret_cast<const half8*>(&smem[row * BN + slot * 8]);
      *reinterpret_cast<half8*>(dst + (long)row * ep.ldc + jc * 8) = hv;
    }
  } else {
#pragma unroll
    for (int mi = 0; mi < MI; ++mi)
#pragma unroll
      for (int ni = 0; ni < NI; ++ni)
#pragma unroll
        for (int reg = 0; reg < 4; ++reg) {
          const int r = (int)m0 + wm * WTM + mi * 16 + g * 4 + reg;
          const int c = (int)n0 + wn * WTN + ni * 16 + r16;
          const float v = acc[mi][ni][reg];
          if constexpr (EPI == EPI_QKV) {
            const float val = v + ep.bias[c];
            const int which = c >> 9;     // 0=q 1=k 2=v
            const int cc2 = c & 511;
            const int h = cc2 >> 6, d = cc2 & 63;
            const int b = r / ep.seq, t = r - b * ep.seq;
            const long bh = (long)(b * Hc + h);
            if (which == 0)      ep.h0[(bh * ep.seq + t) * Dc + d] = (half_t)(val * 0.125f);
            else if (which == 1) ep.h1[(bh * ep.seq + t) * Dc + d] = (half_t)val;
            else                 ep.h2[(bh * Dc + d) * ep.seq + t] = (half_t)val;
          } else {  // EPI_PROJ
            ep.f0[(long)r * Cc + c] = v + ep.bias[c];
          }
        }
  }
}

// ------------------------------------------------- fused softmax + PV
// Per block: 32 q-rows of one z. Streams raw-score tiles S[32][128] and
// V^T tiles [64][128]; online softmax applied in-register (A-operand layout
// == row-major); O accumulated via MFMA in C-layout; normalize at end.
// EPI_AV: 0 -> out = O/l (cval_y2x -> CV2); 1 -> out = O/l - cv_in (DH).
template <int EPI_AV, bool MASKED>
__global__ __launch_bounds__(256) void attnval(
    const half_t* __restrict__ S, const half_t* __restrict__ Vt,
    const int* __restrict__ mask, half_t* __restrict__ outp,
    const half_t* __restrict__ cv_in,
    int Slen, long sS, int Vld, long sV, int zbase)
{
  __shared__ __align__(16) half_t Sbuf[32 * 128];
  __shared__ __align__(16) half_t Vbuf[64 * 128];
  const int tid = threadIdx.x, lane = tid & 63, wave = tid >> 6;
  const int wm = wave >> 1, wn = wave & 1;
  const int r16 = lane & 15, g = lane >> 4;
  const int zi = blockIdx.y;
  const int t0 = blockIdx.x * 32;
  const half_t* Sz = S + (long)zi * sS + (long)t0 * Slen;
  const half_t* Vz = Vt + (long)zi * sV;

  floatx4 O[2];
  O[0] = floatx4{0.f, 0.f, 0.f, 0.f};
  O[1] = floatx4{0.f, 0.f, 0.f, 0.f};
  float m_run = -1e30f, l_run = 0.f;
  const int srow = wm * 16 + r16;     // stats row handled by this lane

  for (int s0 = 0; s0 < Slen; s0 += 128) {
    // stage S (32x16 chunks) and V (64x16 chunks), slot-swizzled fetch
#pragma unroll
    for (int i = 0; i < 2; ++i) {
      const int c = tid + i * 256;
      const int row = c >> 4, js = c & 15;
      const int jg = js ^ (row & 15);
      gld_lds16(Sz + (long)row * Slen + s0 + jg * 8, Sbuf + c * 8);
    }
#pragma unroll
    for (int i = 0; i < 4; ++i) {
      const int c = tid + i * 256;
      const int row = c >> 4, js = c & 15;
      const int jg = js ^ (row & 15);
      gld_lds16(Vz + (long)row * Vld + s0 + jg * 8, Vbuf + c * 8);
    }
    __syncthreads();

    // load this lane's 32 scores (A-layout: row=lane&15, k=g*8 within k-step)
    float sv[4][8];
#pragma unroll
    for (int ks = 0; ks < 4; ++ks) {
      const int slot = (ks * 4 + g) ^ (srow & 15);
      const half8 h = *reinterpret_cast<const half8*>(&Sbuf[srow * 128 + slot * 8]);
#pragma unroll
      for (int j = 0; j < 8; ++j) sv[ks][j] = (float)h[j];
    }
    if constexpr (MASKED) {
      const long mrow = (long)(t0 + srow) * Tc;
#pragma unroll
      for (int ks = 0; ks < 4; ++ks) {
        const int4* mp = reinterpret_cast<const int4*>(mask + mrow + s0 + ks * 32 + g * 8);
        const int4 ma = mp[0], mb = mp[1];
        if (ma.x == 0) sv[ks][0] = -__builtin_inff();
        if (ma.y == 0) sv[ks][1] = -__builtin_inff();
        if (ma.z == 0) sv[ks][2] = -__builtin_inff();
        if (ma.w == 0) sv[ks][3] = -__builtin_inff();
        if (mb.x == 0) sv[ks][4] = -__builtin_inff();
        if (mb.y == 0) sv[ks][5] = -__builtin_inff();
        if (mb.z == 0) sv[ks][6] = -__builtin_inff();
        if (mb.w == 0) sv[ks][7] = -__builtin_inff();
      }
    }
    // online softmax (row reduce across the 4 g-copies of each row)
    float tm = -1e30f;
#pragma unroll
    for (int ks = 0; ks < 4; ++ks)
#pragma unroll
      for (int j = 0; j < 8; ++j) tm = fmaxf(tm, sv[ks][j]);
    tm = fmaxf(tm, __shfl_xor(tm, 16));
    tm = fmaxf(tm, __shfl_xor(tm, 32));
    const float mnew = fmaxf(m_run, tm);
    const float alpha = __expf(m_run - mnew);
    float ps = 0.f;
    half8 pf[4];
#pragma unroll
    for (int ks = 0; ks < 4; ++ks)
#pragma unroll
      for (int j = 0; j < 8; ++j) {
        const float e = __expf(sv[ks][j] - mnew);
        ps += e;
        pf[ks][j] = (half_t)e;
      }
    ps += __shfl_xor(ps, 16);
    ps += __shfl_xor(ps, 32);
    l_run = l_run * alpha + ps;
    m_run = mnew;
    // rescale O (O rows are C-layout g*4+reg; stats live at lane==row)
    float ar[4];
#pragma unroll
    for (int reg = 0; reg < 4; ++reg) ar[reg] = __shfl(alpha, g * 4 + reg);
#pragma unroll
    for (int ni = 0; ni < 2; ++ni)
#pragma unroll
      for (int reg = 0; reg < 4; ++reg) O[ni][reg] *= ar[reg];
    // PV: O[t,d] += P[t,s] * Vt[d,s]
#pragma unroll
    for (int ks = 0; ks < 4; ++ks)
#pragma unroll
      for (int ni = 0; ni < 2; ++ni) {
        const int vrow = wn * 32 + ni * 16 + r16;
        const int slot = (ks * 4 + g) ^ (vrow & 15);
        const half8 bf = *reinterpret_cast<const half8*>(&Vbuf[vrow * 128 + slot * 8]);
        O[ni] = __builtin_amdgcn_mfma_f32_16x16x32_f16(pf[ks], bf, O[ni], 0, 0, 0);
      }
    __syncthreads();
  }

  const float linv = 1.f / l_run;
  float lr[4];
#pragma unroll
  for (int reg = 0; reg < 4; ++reg) lr[reg] = __shfl(linv, g * 4 + reg);
  const int gz = zi + zbase, b = gz >> 3, h = gz & 7;
#pragma unroll
  for (int ni = 0; ni < 2; ++ni)
#pragma unroll
    for (int reg = 0; reg < 4; ++reg) {
      const int t = t0 + wm * 16 + g * 4 + reg;
      const int d = wn * 32 + ni * 16 + r16;
      const long idx = ((long)(b * Tc + t)) * Cc + h * 64 + d;
      const float val = O[ni][reg] * lr[reg];
      if constexpr (EPI_AV == 0) outp[idx] = (half_t)val;
      else                       outp[idx] = (half_t)(val - (float)cv_in[idx]);
    }
}

// ------------------------------------------------------------- fp32 -> f16
typedef _Float16 half4v __attribute__((ext_vector_type(4)));
__global__ void f32_to_f16_k(const float* __restrict__ in, half_t* __restrict__ out, int n4) {
  const int i = blockIdx.x * 256 + threadIdx.x;
  if (i < n4) {
    const float4 f = reinterpret_cast<const float4*>(in)[i];
    half4v h; h[0] = (half_t)f.x; h[1] = (half_t)f.y; h[2] = (half_t)f.z; h[3] = (half_t)f.w;
    reinterpret_cast<half4v*>(out)[i] = h;
  }
}

// ------------------------------------------------------------- workspace map
constexpr size_t OFF_XH    = 0;
constexpr size_t OFF_YH    = OFF_XH    + (size_t)Bc*Tc*Cc*2;
constexpr size_t OFF_WQ    = OFF_YH    + (size_t)Bc*Mc*Cc*2;
constexpr size_t OFF_WP    = OFF_WQ    + (size_t)3*Cc*Cc*2;
constexpr size_t OFF_QX    = OFF_WP    + (size_t)Cc*Cc*2;
constexpr size_t OFF_KX    = OFF_QX    + (size_t)Bc*Hc*Tc*Dc*2;
constexpr size_t OFF_VXT   = OFF_KX    + (size_t)Bc*Hc*Tc*Dc*2;  // [B,H,D,T]
constexpr size_t OFF_QY    = OFF_VXT   + (size_t)Bc*Hc*Tc*Dc*2;
constexpr size_t OFF_KY    = OFF_QY    + (size_t)Bc*Hc*Mc*Dc*2;
constexpr size_t OFF_VYT   = OFF_KY    + (size_t)Bc*Hc*Mc*Dc*2;  // [B,H,D,M]
constexpr size_t OFF_CATT  = OFF_VYT   + (size_t)Bc*Hc*Mc*Dc*2;  // [B,H,T,M]
constexpr size_t OFF_CATTT = OFF_CATT  + (size_t)Bc*Hc*Tc*Mc*2;  // [B,H,T,M]
constexpr size_t OFF_CH    = OFF_CATTT + (size_t)Bc*Hc*Tc*Mc*2;  // [CHUNK_Z,T,T]
constexpr size_t OFF_CV2   = OFF_CH    + (size_t)CHUNK_Z*Tc*Tc*2; // [B,T,C]
constexpr size_t OFF_DH    = OFF_CV2   + (size_t)Bc*Tc*Cc*2;      // [B,T,C]
// total ~203.4 MB

extern "C" void kernel_launch(void* const* d_in, const int* in_sizes, int n_in,
                              void* d_out, int out_size, void* d_ws, size_t ws_size,
                              hipStream_t stream) {
  const float* x      = (const float*)d_in[0];
  const float* y      = (const float*)d_in[1];
  const int*   mask   = (const int*)  d_in[2];
  const float* qkv_b  = (const float*)d_in[4];
  const float* proj_b = (const float*)d_in[6];
  float* out = (float*)d_out;
  char* ws = (char*)d_ws;

  half_t* XH    = (half_t*)(ws + OFF_XH);
  half_t* YH    = (half_t*)(ws + OFF_YH);
  half_t* WQ    = (half_t*)(ws + OFF_WQ);
  half_t* WP    = (half_t*)(ws + OFF_WP);
  half_t* QX    = (half_t*)(ws + OFF_QX);
  half_t* KX    = (half_t*)(ws + OFF_KX);
  half_t* VXT   = (half_t*)(ws + OFF_VXT);
  half_t* QY    = (half_t*)(ws + OFF_QY);
  half_t* KY    = (half_t*)(ws + OFF_KY);
  half_t* VYT   = (half_t*)(ws + OFF_VYT);
  half_t* CATT  = (half_t*)(ws + OFF_CATT);
  half_t* CATTT = (half_t*)(ws + OFF_CATTT);
  half_t* CH    = (half_t*)(ws + OFF_CH);
  half_t* CV2   = (half_t*)(ws + OFF_CV2);
  half_t* DH    = (half_t*)(ws + OFF_DH);

  // fp32 -> f16 converts
  f32_to_f16_k<<<(Bc*Tc*Cc/4 + 255) / 256, 256, 0, stream>>>(x, XH, Bc*Tc*Cc/4);
  f32_to_f16_k<<<(Bc*Mc*Cc/4 + 255) / 256, 256, 0, stream>>>(y, YH, Bc*Mc*Cc/4);
  f32_to_f16_k<<<(3*Cc*Cc/4 + 255) / 256, 256, 0, stream>>>((const float*)d_in[3], WQ, 3*Cc*Cc/4);
  f32_to_f16_k<<<(Cc*Cc/4 + 255) / 256, 256, 0, stream>>>((const float*)d_in[5], WP, Cc*Cc/4);

  // qkv projections
  {
    EpiParams ep{}; ep.h0 = QX; ep.h1 = KX; ep.h2 = VXT; ep.bias = qkv_b; ep.seq = Tc;
    gemm_nt<128,128,2,2,EPI_QKV><<<dim3(12, 32, 1), 256, 0, stream>>>(
        XH, WQ, Cc, Cc, Cc, 0, 0, ep);
  }
  {
    EpiParams ep{}; ep.h0 = QY; ep.h1 = KY; ep.h2 = VYT; ep.bias = qkv_b; ep.seq = Mc;
    gemm_nt<64,128,2,2,EPI_QKV><<<dim3(12, 32, 1), 256, 0, stream>>>(
        YH, WQ, Cc, Cc, Cc, 0, 0, ep);
  }
  // catt_x2y[t,m] = q_x(scaled)[t] . k_y[m]
  {
    EpiParams ep{}; ep.h0 = CATT; ep.scale = 1.f; ep.ldc = Mc; ep.bstride = (long)Tc*Mc;
    gemm_nt<128,128,2,2,EPI_F16STORE><<<dim3(8, 16, Bc*Hc), 256, 0, stream>>>(
        QX, KY, Dc, Dc, Dc, (long)Tc*Dc, (long)Mc*Dc, ep);
  }
  // catt_y2x^T[s,m] = k_x[s] . q_y(scaled)[m]
  {
    EpiParams ep{}; ep.h0 = CATTT; ep.scale = 1.f; ep.ldc = Mc; ep.bstride = (long)Tc*Mc;
    gemm_nt<128,128,2,2,EPI_F16STORE><<<dim3(8, 16, Bc*Hc), 256, 0, stream>>>(
        KX, QY, Dc, Dc, Dc, (long)Tc*Dc, (long)Mc*Dc, ep);
  }

  // Second attention, chunked over z: chained GEMM -> fused softmax+PV
  for (int z0 = 0; z0 < Bc * Hc; z0 += CHUNK_Z) {
    {
      EpiParams ep{}; ep.h0 = CH; ep.scale = 0.125f; ep.ldc = Tc; ep.bstride = (long)Tc*Tc;
      gemm_nt<128,128,2,2,EPI_F16STORE><<<dim3(16, 16, CHUNK_Z), 256, 0, stream>>>(
          CATT + (long)z0*Tc*Mc, CATTT + (long)z0*Tc*Mc,
          Mc, Mc, Mc, (long)Tc*Mc, (long)Tc*Mc, ep);
    }
    attnval<0, true><<<dim3(Tc/32, CHUNK_Z), 256, 0, stream>>>(
        CH, VXT + (long)z0*Dc*Tc, mask, CV2, nullptr,
        Tc, (long)Tc*Tc, Tc, (long)Dc*Tc, z0);
  }

  // First attention: fused softmax(CATT)+PV(VYT), minus CV2 -> DH
  attnval<1, false><<<dim3(Tc/32, Bc*Hc), 256, 0, stream>>>(
      CATT, VYT, nullptr, DH, CV2,
      Mc, (long)Tc*Mc, Mc, (long)Dc*Mc, 0);

  // out = diff @ proj_w^T + proj_b
  {
    EpiParams ep{}; ep.f0 = out; ep.bias = proj_b;
    gemm_nt<128,64,2,2,EPI_PROJ><<<dim3(8, 32, 1), 256, 0, stream>>>(
        DH, WP, Cc, Cc, Cc, 0, 0, ep);
  }
}

// Round 5
// 554.233 us; speedup vs baseline: 1.2219x; 1.2219x over previous
//
#include <hip/hip_runtime.h>

// CrossAttentionPro on MI355X — Round 4:
//  + flash_chained: fused chained-GEMM (K=1024) + mask + online-softmax + PV
//    in one kernel; CH [B,H,T,T] never materialized (removes ~510 MB traffic).
//  + reverted R3 regressions: gemm_nt back to R2 direct-store epilogue,
//    first attention back to R2 softmax_rows + cvaldiff GEMM.
// All matmuls NT; v stored transposed; catt_y2x computed transposed.

typedef _Float16 half_t;
typedef _Float16 half8 __attribute__((ext_vector_type(8)));
typedef float floatx4 __attribute__((ext_vector_type(4)));

constexpr int Bc = 2, Tc = 2048, Mc = 1024, Cc = 512, Hc = 8, Dc = 64;

enum { EPI_F16STORE = 0, EPI_QKV = 1, EPI_CVALDIFF = 2, EPI_PROJ = 3 };

struct EpiParams {
  half_t* h0;        // primary f16 dest
  half_t* h1;        // k (QKV) / CV2 source (CVALDIFF)
  half_t* h2;        // v^T (QKV)
  float* f0;         // final fp32 out (PROJ)
  const float* bias;
  float scale;
  int ldc;
  long bstride;
  int seq;
};

// async global->LDS, 16B per lane; dst must be wave-uniform base + lane*16.
__device__ __forceinline__ void gld_lds16(const half_t* g, half_t* l) {
  __builtin_amdgcn_global_load_lds(
      (const __attribute__((address_space(1))) void*)g,
      (__attribute__((address_space(3))) void*)l, 16, 0, 0);
}

// ---------------------------------------------------------------- GEMM (NT)
// R2-proven kernel: C[r,c] = sum_k A[r,k]*Bt[c,k], BK=32 swizzled async
// staging (measured 0 bank conflicts), direct per-element epilogue.
template <int BM, int BN, int WMG, int WNG, int EPI>
__global__ __launch_bounds__(256) void gemm_nt(
    const half_t* __restrict__ A, const half_t* __restrict__ Bt,
    int K, int lda, int ldb, long bsA, long bsB, EpiParams ep)
{
  constexpr int BK = 32;
  constexpr int WTM = BM / WMG, WTN = BN / WNG;
  constexpr int MI = WTM / 16, NI = WTN / 16;
  constexpr int ACHUNKS = BM * 4;
  constexpr int BCHUNKS = BN * 4;
  __shared__ __align__(16) half_t As[BM * BK];
  __shared__ __align__(16) half_t Bs[BN * BK];

  const int tid = threadIdx.x;
  const int lane = tid & 63;
  const int wave = tid >> 6;
  const int wm = wave / WNG, wn = wave % WNG;
  const int r16 = lane & 15, g = lane >> 4;
  const int z = blockIdx.z;
  const long m0 = (long)blockIdx.y * BM;
  const long n0 = (long)blockIdx.x * BN;
  const half_t* Abase = A + (long)z * bsA + m0 * (long)lda;
  const half_t* Bbase = Bt + (long)z * bsB + n0 * (long)ldb;

  const int rA = wm * WTM + r16;
  const int rB = wn * WTN + r16;
  const int swA = (g ^ ((rA >> 1) & 3)) * 8;
  const int swB = (g ^ ((rB >> 1) & 3)) * 8;

  floatx4 acc[MI][NI];
#pragma unroll
  for (int mi = 0; mi < MI; ++mi)
#pragma unroll
    for (int ni = 0; ni < NI; ++ni)
      acc[mi][ni] = floatx4{0.f, 0.f, 0.f, 0.f};

  for (int kt = 0; kt < K; kt += BK) {
#pragma unroll
    for (int i = 0; i < (ACHUNKS + 255) / 256; ++i) {
      const int c = tid + i * 256;
      if (ACHUNKS % 256 == 0 || c < ACHUNKS) {
        const int row = c >> 2, js = c & 3;
        const int jg = js ^ ((row >> 1) & 3);
        gld_lds16(Abase + (long)row * lda + kt + jg * 8, As + c * 8);
      }
    }
#pragma unroll
    for (int i = 0; i < (BCHUNKS + 255) / 256; ++i) {
      const int c = tid + i * 256;
      if (BCHUNKS % 256 == 0 || c < BCHUNKS) {
        const int row = c >> 2, js = c & 3;
        const int jg = js ^ ((row >> 1) & 3);
        gld_lds16(Bbase + (long)row * ldb + kt + jg * 8, Bs + c * 8);
      }
    }
    __syncthreads();
    half8 aF[MI], bF[NI];
#pragma unroll
    for (int mi = 0; mi < MI; ++mi)
      aF[mi] = *reinterpret_cast<const half8*>(&As[(rA + mi * 16) * BK + swA]);
#pragma unroll
    for (int ni = 0; ni < NI; ++ni)
      bF[ni] = *reinterpret_cast<const half8*>(&Bs[(rB + ni * 16) * BK + swB]);
#pragma unroll
    for (int mi = 0; mi < MI; ++mi)
#pragma unroll
      for (int ni = 0; ni < NI; ++ni)
        acc[mi][ni] = __builtin_amdgcn_mfma_f32_16x16x32_f16(aF[mi], bF[ni], acc[mi][ni], 0, 0, 0);
    __syncthreads();
  }

  // epilogue: C/D layout col=lane&15, row=(lane>>4)*4+reg  [m89-verified]
#pragma unroll
  for (int mi = 0; mi < MI; ++mi) {
#pragma unroll
    for (int ni = 0; ni < NI; ++ni) {
#pragma unroll
      for (int reg = 0; reg < 4; ++reg) {
        const int r = (int)m0 + wm * WTM + mi * 16 + g * 4 + reg;
        const int c = (int)n0 + wn * WTN + ni * 16 + r16;
        const float v = acc[mi][ni][reg];
        if constexpr (EPI == EPI_F16STORE) {
          ep.h0[(long)z * ep.bstride + (long)r * ep.ldc + c] = (half_t)(v * ep.scale);
        } else if constexpr (EPI == EPI_QKV) {
          const float val = v + ep.bias[c];
          const int which = c >> 9;     // 0=q 1=k 2=v
          const int cc2 = c & 511;
          const int h = cc2 >> 6, d = cc2 & 63;
          const int b = r / ep.seq, t = r - b * ep.seq;
          const long bh = (long)(b * Hc + h);
          if (which == 0)      ep.h0[(bh * ep.seq + t) * Dc + d] = (half_t)(val * 0.125f);
          else if (which == 1) ep.h1[(bh * ep.seq + t) * Dc + d] = (half_t)val;
          else                 ep.h2[(bh * Dc + d) * ep.seq + t] = (half_t)val;
        } else if constexpr (EPI == EPI_CVALDIFF) {
          const int b = z >> 3, h = z & 7;
          const long idx = ((long)(b * Tc + r)) * Cc + h * Dc + c;
          ep.h0[idx] = (half_t)(v - (float)ep.h1[idx]); // diff = cval_x2y - cval_y2x
        } else {  // EPI_PROJ
          ep.f0[(long)r * Cc + c] = v + ep.bias[c];
        }
      }
    }
  }
}

// --------------------------------------------- flash chained attention
// Per block: 64 q-rows of one z, loop s-tiles of 128 over all T=2048 s.
// S-tile = 0.125 * CATT[q,:]·CATTT[s,:]^T (K=1024, R2 GEMM inner loop),
// masked online softmax in C-layout registers (row = g*4+reg is lane-local
// for both S and O -> alpha needs no shuffle; row reductions = shfl_xor
// over r16), P -> LDS (pad-136) -> A-layout -> PV MFMA with VXT tiles.
// Output: cval_y2x -> CV2 [B,T,C] (head-scattered), f16.
__global__ __launch_bounds__(256, 2) void flash_chained(
    const half_t* __restrict__ CATT, const half_t* __restrict__ CATTT,
    const half_t* __restrict__ VXT, const int* __restrict__ mask,
    half_t* __restrict__ CV2)
{
  constexpr int QT = 64, ST = 128, BK = 32;
  // uni: union{ As[64*32]=2048 + Bs[128*32]=4096 halfs | P 4 waves*16*136 }
  __shared__ __align__(16) half_t uni[8704];
  __shared__ __align__(16) half_t Vb[8192];   // 4 sub-tiles [64][32]
  half_t* As = uni;
  half_t* Bs = uni + 2048;

  const int tid = threadIdx.x, lane = tid & 63, w = tid >> 6;
  const int r16 = lane & 15, g = lane >> 4;
  const int z = blockIdx.y, q0 = blockIdx.x * QT;
  const int b = z >> 3, h = z & 7;
  const half_t* Ab = CATT + ((long)z * Tc + q0) * Mc;
  const half_t* Bb = CATTT + (long)z * Tc * Mc;
  const half_t* Vbase = VXT + (long)z * Dc * Tc;

  const int sw = (g ^ ((r16 >> 1) & 3)) * 8;   // R2 swizzle (row bits1-2 = r16 bits1-2)

  floatx4 oacc[4];
#pragma unroll
  for (int no = 0; no < 4; ++no) oacc[no] = floatx4{0.f, 0.f, 0.f, 0.f};
  float mrun[4], lrun[4];
#pragma unroll
  for (int reg = 0; reg < 4; ++reg) { mrun[reg] = -1e30f; lrun[reg] = 0.f; }

  for (int s0 = 0; s0 < Tc; s0 += ST) {
    // stage V: 4 sub-tiles [64 d][32 s], R2 swizzle inside each (1024 chunks)
#pragma unroll
    for (int i = 0; i < 4; ++i) {
      const int c = tid + i * 256;
      const int sub = c >> 8, cc = c & 255;
      const int d = cc >> 2, js = cc & 3;
      const int jg = js ^ ((d >> 1) & 3);
      gld_lds16(Vbase + (long)d * Tc + s0 + sub * 32 + jg * 8, Vb + c * 8);
    }
    floatx4 sacc[8];
#pragma unroll
    for (int ni = 0; ni < 8; ++ni) sacc[ni] = floatx4{0.f, 0.f, 0.f, 0.f};

    for (int kt = 0; kt < Mc; kt += BK) {
      {  // As: 64 rows x 4 chunks = 256 -> 1/thread
        const int row = tid >> 2, js = tid & 3;
        const int jg = js ^ ((row >> 1) & 3);
        gld_lds16(Ab + (long)row * Mc + kt + jg * 8, As + tid * 8);
      }
#pragma unroll
      for (int i = 0; i < 2; ++i) {  // Bs: 128 x 4 = 512 -> 2/thread
        const int c = tid + i * 256;
        const int row = c >> 2, js = c & 3;
        const int jg = js ^ ((row >> 1) & 3);
        gld_lds16(Bb + ((long)(s0 + row)) * Mc + kt + jg * 8, Bs + c * 8);
      }
      __syncthreads();
      const half8 aF = *reinterpret_cast<const half8*>(&As[(w * 16 + r16) * BK + sw]);
#pragma unroll
      for (int ni = 0; ni < 8; ++ni) {
        const half8 bF = *reinterpret_cast<const half8*>(&Bs[(ni * 16 + r16) * BK + sw]);
        sacc[ni] = __builtin_amdgcn_mfma_f32_16x16x32_f16(aF, bF, sacc[ni], 0, 0, 0);
      }
      __syncthreads();
    }

    // ---- masked online softmax on sacc (C-layout) ----
    float sv[8][4];
#pragma unroll
    for (int ni = 0; ni < 8; ++ni)
#pragma unroll
      for (int reg = 0; reg < 4; ++reg) sv[ni][reg] = sacc[ni][reg] * 0.125f;
#pragma unroll
    for (int reg = 0; reg < 4; ++reg) {
      const long trow = (long)(q0 + w * 16 + g * 4 + reg) * Tc + s0;
#pragma unroll
      for (int ni = 0; ni < 8; ++ni)
        if (mask[trow + ni * 16 + r16] == 0) sv[ni][reg] = -__builtin_inff();
    }
#pragma unroll
    for (int reg = 0; reg < 4; ++reg) {
      float tm = sv[0][reg];
#pragma unroll
      for (int ni = 1; ni < 8; ++ni) tm = fmaxf(tm, sv[ni][reg]);
      tm = fmaxf(tm, __shfl_xor(tm, 1));
      tm = fmaxf(tm, __shfl_xor(tm, 2));
      tm = fmaxf(tm, __shfl_xor(tm, 4));
      tm = fmaxf(tm, __shfl_xor(tm, 8));
      const float mnew = fmaxf(mrun[reg], tm);
      const float alpha = __expf(mrun[reg] - mnew);
      mrun[reg] = mnew;
      float ps = 0.f;
#pragma unroll
      for (int ni = 0; ni < 8; ++ni) {
        const float e = __expf(sv[ni][reg] - mnew);
        ps += e;
        // P -> LDS (wave-private slab, pad 136): row=g*4+reg, col=ni*16+r16
        uni[w * 2176 + (g * 4 + reg) * 136 + ni * 16 + r16] = (half_t)e;
      }
      ps += __shfl_xor(ps, 1);
      ps += __shfl_xor(ps, 2);
      ps += __shfl_xor(ps, 4);
      ps += __shfl_xor(ps, 8);
      lrun[reg] = lrun[reg] * alpha + ps;
#pragma unroll
      for (int no = 0; no < 4; ++no) oacc[no][reg] *= alpha;
    }

    // ---- PV: O[t,d] += P[t,s]·VXT[d,s] ----
#pragma unroll
    for (int ks2 = 0; ks2 < 4; ++ks2) {
      const half8 aP = *reinterpret_cast<const half8*>(
          &uni[w * 2176 + r16 * 136 + ks2 * 32 + g * 8]);
#pragma unroll
      for (int no = 0; no < 4; ++no) {
        const half8 bV = *reinterpret_cast<const half8*>(
            &Vb[ks2 * 2048 + (no * 16 + r16) * BK + sw]);
        oacc[no] = __builtin_amdgcn_mfma_f32_16x16x32_f16(aP, bV, oacc[no], 0, 0, 0);
      }
    }
    __syncthreads();  // protect uni(P) + Vb before next s-tile staging
  }

  // epilogue: O/l -> CV2[b, t, h*64+d]
#pragma unroll
  for (int reg = 0; reg < 4; ++reg) {
    const float linv = 1.f / lrun[reg];
    const int t = q0 + w * 16 + g * 4 + reg;
#pragma unroll
    for (int no = 0; no < 4; ++no) {
      const int d = no * 16 + r16;
      CV2[((long)(b * Tc + t)) * Cc + h * 64 + d] = (half_t)(oacc[no][reg] * linv);
    }
  }
}

// ------------------------------------------------------------- row softmax
__device__ inline float wave_red_max(float v) {
#pragma unroll
  for (int o = 32; o > 0; o >>= 1) v = fmaxf(v, __shfl_xor(v, o));
  return v;
}
__device__ inline float wave_red_sum(float v) {
#pragma unroll
  for (int o = 32; o > 0; o >>= 1) v += __shfl_xor(v, o);
  return v;
}

template <int NC>
__global__ __launch_bounds__(256) void softmax_rows(half_t* __restrict__ buf)
{
  constexpr int VEC = NC / 256;
  typedef _Float16 hvec __attribute__((ext_vector_type(VEC)));
  const long row = blockIdx.x;
  const int tid = threadIdx.x, lane = tid & 63, wave = tid >> 6;
  half_t* p = buf + row * NC + tid * VEC;
  __shared__ float red[4];

  float v[VEC];
  hvec hv = *reinterpret_cast<const hvec*>(p);
#pragma unroll
  for (int i = 0; i < VEC; ++i) v[i] = (float)hv[i];
  float mx = -3.0e38f;
#pragma unroll
  for (int i = 0; i < VEC; ++i) mx = fmaxf(mx, v[i]);
  mx = wave_red_max(mx);
  if (lane == 0) red[wave] = mx;
  __syncthreads();
  mx = fmaxf(fmaxf(red[0], red[1]), fmaxf(red[2], red[3]));
  __syncthreads();
  float s = 0.f;
#pragma unroll
  for (int i = 0; i < VEC; ++i) {
    v[i] = __expf(v[i] - mx);
    s += v[i];
  }
  s = wave_red_sum(s);
  if (lane == 0) red[wave] = s;
  __syncthreads();
  s = red[0] + red[1] + red[2] + red[3];
  const float inv = 1.f / s;
  hvec res;
#pragma unroll
  for (int i = 0; i < VEC; ++i) res[i] = (half_t)(v[i] * inv);
  *reinterpret_cast<hvec*>(p) = res;
}

// ------------------------------------------------------------- fp32 -> f16
typedef _Float16 half4v __attribute__((ext_vector_type(4)));
__global__ void f32_to_f16_k(const float* __restrict__ in, half_t* __restrict__ out, int n4) {
  const int i = blockIdx.x * 256 + threadIdx.x;
  if (i < n4) {
    const float4 f = reinterpret_cast<const float4*>(in)[i];
    half4v h; h[0] = (half_t)f.x; h[1] = (half_t)f.y; h[2] = (half_t)f.z; h[3] = (half_t)f.w;
    reinterpret_cast<half4v*>(out)[i] = h;
  }
}

// ------------------------------------------------------------- workspace map
constexpr size_t OFF_XH    = 0;
constexpr size_t OFF_YH    = OFF_XH    + (size_t)Bc*Tc*Cc*2;
constexpr size_t OFF_WQ    = OFF_YH    + (size_t)Bc*Mc*Cc*2;
constexpr size_t OFF_WP    = OFF_WQ    + (size_t)3*Cc*Cc*2;
constexpr size_t OFF_QX    = OFF_WP    + (size_t)Cc*Cc*2;
constexpr size_t OFF_KX    = OFF_QX    + (size_t)Bc*Hc*Tc*Dc*2;
constexpr size_t OFF_VXT   = OFF_KX    + (size_t)Bc*Hc*Tc*Dc*2;  // [B,H,D,T]
constexpr size_t OFF_QY    = OFF_VXT   + (size_t)Bc*Hc*Tc*Dc*2;
constexpr size_t OFF_KY    = OFF_QY    + (size_t)Bc*Hc*Mc*Dc*2;
constexpr size_t OFF_VYT   = OFF_KY    + (size_t)Bc*Hc*Mc*Dc*2;  // [B,H,D,M]
constexpr size_t OFF_CATT  = OFF_VYT   + (size_t)Bc*Hc*Mc*Dc*2;  // [B,H,T,M]
constexpr size_t OFF_CATTT = OFF_CATT  + (size_t)Bc*Hc*Tc*Mc*2;  // [B,H,T,M]
constexpr size_t OFF_CV2   = OFF_CATTT + (size_t)Bc*Hc*Tc*Mc*2;  // [B,T,C]
constexpr size_t OFF_DH    = OFF_CV2   + (size_t)Bc*Tc*Cc*2;     // [B,T,C]
// total ~171 MB (CH buffer eliminated)

extern "C" void kernel_launch(void* const* d_in, const int* in_sizes, int n_in,
                              void* d_out, int out_size, void* d_ws, size_t ws_size,
                              hipStream_t stream) {
  const float* x      = (const float*)d_in[0];
  const float* y      = (const float*)d_in[1];
  const int*   mask   = (const int*)  d_in[2];
  const float* qkv_b  = (const float*)d_in[4];
  const float* proj_b = (const float*)d_in[6];
  float* out = (float*)d_out;
  char* ws = (char*)d_ws;

  half_t* XH    = (half_t*)(ws + OFF_XH);
  half_t* YH    = (half_t*)(ws + OFF_YH);
  half_t* WQ    = (half_t*)(ws + OFF_WQ);
  half_t* WP    = (half_t*)(ws + OFF_WP);
  half_t* QX    = (half_t*)(ws + OFF_QX);
  half_t* KX    = (half_t*)(ws + OFF_KX);
  half_t* VXT   = (half_t*)(ws + OFF_VXT);
  half_t* QY    = (half_t*)(ws + OFF_QY);
  half_t* KY    = (half_t*)(ws + OFF_KY);
  half_t* VYT   = (half_t*)(ws + OFF_VYT);
  half_t* CATT  = (half_t*)(ws + OFF_CATT);
  half_t* CATTT = (half_t*)(ws + OFF_CATTT);
  half_t* CV2   = (half_t*)(ws + OFF_CV2);
  half_t* DH    = (half_t*)(ws + OFF_DH);

  // fp32 -> f16 converts
  f32_to_f16_k<<<(Bc*Tc*Cc/4 + 255) / 256, 256, 0, stream>>>(x, XH, Bc*Tc*Cc/4);
  f32_to_f16_k<<<(Bc*Mc*Cc/4 + 255) / 256, 256, 0, stream>>>(y, YH, Bc*Mc*Cc/4);
  f32_to_f16_k<<<(3*Cc*Cc/4 + 255) / 256, 256, 0, stream>>>((const float*)d_in[3], WQ, 3*Cc*Cc/4);
  f32_to_f16_k<<<(Cc*Cc/4 + 255) / 256, 256, 0, stream>>>((const float*)d_in[5], WP, Cc*Cc/4);

  // qkv projections
  {
    EpiParams ep{}; ep.h0 = QX; ep.h1 = KX; ep.h2 = VXT; ep.bias = qkv_b; ep.seq = Tc;
    gemm_nt<128,128,2,2,EPI_QKV><<<dim3(12, 32, 1), 256, 0, stream>>>(
        XH, WQ, Cc, Cc, Cc, 0, 0, ep);
  }
  {
    EpiParams ep{}; ep.h0 = QY; ep.h1 = KY; ep.h2 = VYT; ep.bias = qkv_b; ep.seq = Mc;
    gemm_nt<64,128,2,2,EPI_QKV><<<dim3(12, 32, 1), 256, 0, stream>>>(
        YH, WQ, Cc, Cc, Cc, 0, 0, ep);
  }
  // catt_x2y[t,m] = q_x(scaled)[t] . k_y[m]
  {
    EpiParams ep{}; ep.h0 = CATT; ep.scale = 1.f; ep.ldc = Mc; ep.bstride = (long)Tc*Mc;
    gemm_nt<128,128,2,2,EPI_F16STORE><<<dim3(8, 16, Bc*Hc), 256, 0, stream>>>(
        QX, KY, Dc, Dc, Dc, (long)Tc*Dc, (long)Mc*Dc, ep);
  }
  // catt_y2x^T[s,m] = k_x[s] . q_y(scaled)[m]
  {
    EpiParams ep{}; ep.h0 = CATTT; ep.scale = 1.f; ep.ldc = Mc; ep.bstride = (long)Tc*Mc;
    gemm_nt<128,128,2,2,EPI_F16STORE><<<dim3(8, 16, Bc*Hc), 256, 0, stream>>>(
        KX, QY, Dc, Dc, Dc, (long)Tc*Dc, (long)Mc*Dc, ep);
  }

  // Second attention fully fused: CH never materialized.
  flash_chained<<<dim3(Tc/64, Bc*Hc), 256, 0, stream>>>(CATT, CATTT, VXT, mask, CV2);

  // First attention: softmax over m (in-place on CATT, raw scores consumed)
  softmax_rows<Mc><<<Bc*Hc*Tc, 256, 0, stream>>>(CATT);
  // cval_x2y[t,d] = sum_m P[t,m]*vT_y[d,m]; DH = cval_x2y - CV2
  {
    EpiParams ep{}; ep.h0 = DH; ep.h1 = CV2;
    gemm_nt<32,64,2,2,EPI_CVALDIFF><<<dim3(1, 64, Bc*Hc), 256, 0, stream>>>(
        CATT, VYT, Mc, Mc, Mc, (long)Tc*Mc, (long)Dc*Mc, ep);
  }
  // out = diff @ proj_w^T + proj_b
  {
    EpiParams ep{}; ep.f0 = out; ep.bias = proj_b;
    gemm_nt<128,64,2,2,EPI_PROJ><<<dim3(8, 32, 1), 256, 0, stream>>>(
        DH, WP, Cc, Cc, Cc, 0, 0, ep);
  }
}